// Round 2
// baseline (222.090 us; speedup 1.0000x reference)
//
#include <hip/hip_runtime.h>

#define NB 128
#define CC 1024
#define HWP 196
#define HH 14
#define OO 256

typedef unsigned short ushort_t;
typedef __attribute__((ext_vector_type(8))) short short8;
typedef __attribute__((ext_vector_type(4))) float float4v;

__device__ __forceinline__ ushort_t f2bf(float v) {
  union { float f; unsigned int u; } c; c.f = v;
  unsigned int u = c.u;
  unsigned int r = (u + 0x7FFFu + ((u >> 16) & 1u)) >> 16;   // RNE
  return (ushort_t)r;
}

// K1: partial channel-sum: partial[n][cg][p] = sum_{c in group} x[n][c][p]
__global__ __launch_bounds__(256) void k_reduce(const float* __restrict__ x,
                                                float* __restrict__ partial) {
  int n = blockIdx.x, cg = blockIdx.y;
  int p = threadIdx.x;
  if (p >= HWP) return;
  const float* base = x + ((size_t)n * CC + (size_t)cg * 128) * HWP + p;
  float s = 0.f;
  #pragma unroll 8
  for (int c = 0; c < 128; ++c) s += base[(size_t)c * HWP];
  partial[(n * 8 + cg) * HWP + p] = s;
}

// K2: exact stable argsort(-fre) rank selection; writes scene + rows/cols outputs
__global__ __launch_bounds__(256) void k_select(const float* __restrict__ partial,
                                                int* __restrict__ scene,
                                                float* __restrict__ out) {
  int n = blockIdx.x, t = threadIdx.x;
  __shared__ float fre[HWP];
  __shared__ int sc[32];
  if (t < HWP) {
    float s = 0.f;
    #pragma unroll
    for (int g = 0; g < 8; ++g) s += partial[(n * 8 + g) * HWP + t];
    fre[t] = s;
  }
  __syncthreads();
  if (t < HWP) {
    float v = fre[t];
    int rank = 0;
    for (int q = 0; q < HWP; ++q) {
      float u = fre[q];
      rank += ((u > v) || (u == v && q < t)) ? 1 : 0;
    }
    if (rank < 16) sc[rank] = t;                       // maxK: ranks 0..15
    else if (rank >= 89 && rank < 105) sc[rank - 73] = t;  // medK: ranks 89..104
  }
  __syncthreads();
  if (t < 32) {
    int p = sc[t];
    scene[n * 32 + t] = p;
    out[2 * NB * 4096 + n * 32 + t] = (float)(p / HH);            // rows
    out[2 * NB * 4096 + NB * 32 + n * 32 + t] = (float)(p % HH);  // cols
  }
}

// K3: coalesced gather: stream x rows through LDS, extract 32 scene columns,
// write dense bf16 nodes[n][j<32][c<1024]. Replaces k_main's scattered gather
// (537 MB line-granular traffic -> 103 MB coalesced + 8 MB writes).
__global__ __launch_bounds__(256) void k_gather(const float* __restrict__ x,
                                                const int* __restrict__ scene,
                                                ushort_t* __restrict__ nodes) {
  int n = blockIdx.x, cs = blockIdx.y, t = threadIdx.x;
  __shared__ alignas(16) float buf[8 * HWP];   // 6272 B: 8 channel-rows
  __shared__ int s_sh[32];
  if (t < 32) s_sh[t] = scene[n * 32 + t];
  const int jj = t >> 3, cc = t & 7;          // 32 j x 8 c per extract pass
  for (int c0 = 0; c0 < 128; c0 += 8) {
    const float4* src = (const float4*)(x + ((size_t)n * CC + (size_t)cs * 128 + c0) * HWP);
    __syncthreads();                           // buf reuse + (iter0) s_sh
    for (int i = t; i < (8 * HWP) / 4; i += 256) ((float4*)buf)[i] = src[i];
    __syncthreads();
    float v = buf[cc * HWP + s_sh[jj]];
    nodes[((size_t)n * 32 + jj) * CC + (size_t)cs * 128 + c0 + cc] = f2bf(v);
  }
}

// K4: cast weights to bf16; wb[z][o][k] layout == w row-major (MFMA B-friendly)
__global__ __launch_bounds__(256) void k_convw(const float* __restrict__ wmax,
                                               const float* __restrict__ wmed,
                                               ushort_t* __restrict__ wb) {
  int idx = blockIdx.x * 256 + threadIdx.x;
  int z = idx >> 18;
  int r = idx & (OO * CC - 1);
  const float* w = z ? wmed : wmax;
  wb[idx] = f2bf(w[r]);
}

// K5: bf16 MFMA GEMM + BN + ReLU + Lnorm apply. One block per (n,z), 4 waves.
__global__ __launch_bounds__(256) void k_main(
    const ushort_t* __restrict__ nodes, const ushort_t* __restrict__ wb,
    const float* __restrict__ g_max, const float* __restrict__ b_max,
    const float* __restrict__ m_max, const float* __restrict__ v_max,
    const float* __restrict__ g_med, const float* __restrict__ b_med,
    const float* __restrict__ m_med, const float* __restrict__ v_med,
    const int* __restrict__ scene, float* __restrict__ out) {
  constexpr int AP = 1032;               // padded row stride (ushorts)
  __shared__ ushort_t A_sh[16 * AP];
  __shared__ float Lsh[16][17];
  __shared__ float dinv[16];
  __shared__ int s_sh[16];
  __shared__ float y_sh[16][257];

  const int n = blockIdx.x;
  const int z = blockIdx.y;
  const int t = threadIdx.x;

  if (t < 16) s_sh[t] = scene[n * 32 + z * 16 + t];

  // stage A (16 x 1024 bf16) from nodes — fully coalesced 16B/lane
  {
    const ushort_t* src = nodes + ((size_t)n * 32 + (size_t)z * 16) * CC;
    #pragma unroll
    for (int i = t; i < 2048; i += 256) {
      int j = i >> 7, c8 = i & 127;
      *reinterpret_cast<short8*>(&A_sh[j * AP + c8 * 8]) =
          *reinterpret_cast<const short8*>(&src[j * CC + c8 * 8]);
    }
  }
  __syncthreads();   // s_sh + A_sh visible

  {
    const int i = t >> 4, j = t & 15;
    int pi = s_sh[i], pj = s_sh[j];
    float dr = (float)(pi / HH - pj / HH);
    float dc = (float)(pi % HH - pj % HH);
    Lsh[i][j] = 1.0f / (1.0f + sqrtf(dr * dr + dc * dc));
  }
  __syncthreads();
  if (t < 16) {
    float s = 0.f;
    #pragma unroll
    for (int j = 0; j < 16; ++j) s += Lsh[t][j];
    dinv[t] = rsqrtf(s);
  }

  const int w = t >> 6;
  const int l = t & 63;
  const int m = l & 15;
  const int quad = l >> 4;

  const ushort_t* Arow = &A_sh[m * AP + quad * 8];
  const ushort_t* B0 = wb + (size_t)z * (OO * CC) + (size_t)(w * 64 + m) * CC + quad * 8;

  float4v acc0 = {0.f, 0.f, 0.f, 0.f};
  float4v acc1 = acc0, acc2 = acc0, acc3 = acc0;

  __syncthreads();   // dinv visible

  #pragma unroll 4
  for (int k0 = 0; k0 < CC; k0 += 32) {
    short8 a  = *reinterpret_cast<const short8*>(Arow + k0);
    short8 b0 = *reinterpret_cast<const short8*>(B0 + k0);
    short8 b1 = *reinterpret_cast<const short8*>(B0 + 16 * CC + k0);
    short8 b2 = *reinterpret_cast<const short8*>(B0 + 32 * CC + k0);
    short8 b3 = *reinterpret_cast<const short8*>(B0 + 48 * CC + k0);
    acc0 = __builtin_amdgcn_mfma_f32_16x16x32_bf16(a, b0, acc0, 0, 0, 0);
    acc1 = __builtin_amdgcn_mfma_f32_16x16x32_bf16(a, b1, acc1, 0, 0, 0);
    acc2 = __builtin_amdgcn_mfma_f32_16x16x32_bf16(a, b2, acc2, 0, 0, 0);
    acc3 = __builtin_amdgcn_mfma_f32_16x16x32_bf16(a, b3, acc3, 0, 0, 0);
  }

  const float* gp = z ? g_med : g_max;
  const float* bp = z ? b_med : b_max;
  const float* mp = z ? m_med : m_max;
  const float* vp = z ? v_med : v_max;

  // BN + ReLU; scatter C-layout (col=lane&15, row=quad*4+reg) to LDS
  #pragma unroll
  for (int tt = 0; tt < 4; ++tt) {
    float4v av = (tt == 0) ? acc0 : (tt == 1) ? acc1 : (tt == 2) ? acc2 : acc3;
    int o = w * 64 + tt * 16 + m;
    float sc = gp[o] * rsqrtf(vp[o] + 1e-5f);
    float sh = bp[o] - mp[o] * sc;
    #pragma unroll
    for (int r = 0; r < 4; ++r) {
      int j = quad * 4 + r;
      float y = av[r] * sc + sh;
      y = fmaxf(y, 0.f);
      y_sh[j][o] = y * dinv[j];
    }
  }
  __syncthreads();

  // out[n,z,i,o] = dinv_i * sum_j L[i][j] * (dinv_j * y[j][o]); thread = o
  float yp[16];
  #pragma unroll
  for (int j = 0; j < 16; ++j) yp[j] = y_sh[j][t];
  float* ob = out + (size_t)z * (NB * 4096) + (size_t)n * 4096 + t;
  #pragma unroll
  for (int i = 0; i < 16; ++i) {
    float s = 0.f;
    #pragma unroll
    for (int j = 0; j < 16; ++j) s = fmaf(Lsh[i][j], yp[j], s);
    ob[(size_t)i * OO] = s * dinv[i];
  }
}

extern "C" void kernel_launch(void* const* d_in, const int* in_sizes, int n_in,
                              void* d_out, int out_size, void* d_ws, size_t ws_size,
                              hipStream_t stream) {
  const float* x     = (const float*)d_in[0];
  const float* w_max = (const float*)d_in[2];
  const float* g_max = (const float*)d_in[3];
  const float* b_max = (const float*)d_in[4];
  const float* m_max = (const float*)d_in[5];
  const float* v_max = (const float*)d_in[6];
  const float* w_med = (const float*)d_in[7];
  const float* g_med = (const float*)d_in[8];
  const float* b_med = (const float*)d_in[9];
  const float* m_med = (const float*)d_in[10];
  const float* v_med = (const float*)d_in[11];
  float* out = (float*)d_out;

  float* ws_f = (float*)d_ws;
  float* partial  = ws_f;                        // 200704 floats
  int* scene      = (int*)(ws_f + 200704);       // 4096 ints
  ushort_t* wb    = (ushort_t*)(ws_f + 204800);  // 524288 ushorts (1 MB)
  ushort_t* nodes = (ushort_t*)(ws_f + 466944);  // 128*32*1024 ushorts (8 MB)

  k_reduce<<<dim3(NB, 8), 256, 0, stream>>>(x, partial);
  k_select<<<dim3(NB), 256, 0, stream>>>(partial, scene, out);
  k_convw<<<dim3((2 * OO * CC) / 256), 256, 0, stream>>>(w_max, w_med, wb);
  k_gather<<<dim3(NB, 8), 256, 0, stream>>>(x, scene, nodes);
  k_main<<<dim3(NB, 2), 256, 0, stream>>>(nodes, wb, g_max, b_max, m_max, v_max,
                                          g_med, b_med, m_med, v_med, scene, out);
}

// Round 3
// 218.653 us; speedup vs baseline: 1.0157x; 1.0157x over previous
//
#include <hip/hip_runtime.h>

#define NB 128
#define CC 1024
#define HWP 196
#define HH 14
#define OO 256

typedef unsigned short ushort_t;
typedef __attribute__((ext_vector_type(8))) short short8;
typedef __attribute__((ext_vector_type(4))) float float4v;

__device__ __forceinline__ ushort_t f2bf(float v) {
  union { float f; unsigned int u; } c; c.f = v;
  unsigned int u = c.u;
  unsigned int r = (u + 0x7FFFu + ((u >> 16) & 1u)) >> 16;   // RNE
  return (ushort_t)r;
}

// K1: partial channel-sum: partial[n][cg][p] = sum_{c in group} x[n][c][p]
__global__ __launch_bounds__(256) void k_reduce(const float* __restrict__ x,
                                                float* __restrict__ partial) {
  int n = blockIdx.x, cg = blockIdx.y;
  int p = threadIdx.x;
  if (p >= HWP) return;
  const float* base = x + ((size_t)n * CC + (size_t)cg * 128) * HWP + p;
  float s = 0.f;
  #pragma unroll 16
  for (int c = 0; c < 128; ++c) s += base[(size_t)c * HWP];
  partial[(n * 8 + cg) * HWP + p] = s;
}

// K2: fused (a) exact stable argsort(-fre) rank selection -> scene + rows/cols,
//           (b) weight bf16 cast. Disjoint block ranges; independent work.
__global__ __launch_bounds__(256) void k_misc(const float* __restrict__ partial,
                                              const float* __restrict__ wmax,
                                              const float* __restrict__ wmed,
                                              int* __restrict__ scene,
                                              float* __restrict__ out,
                                              ushort_t* __restrict__ wb) {
  int b = blockIdx.x, t = threadIdx.x;
  if (b >= NB) {  // convw part: blocks NB .. NB+2047
    int idx = (b - NB) * 256 + t;
    int z = idx >> 18;
    int r = idx & (OO * CC - 1);
    const float* w = z ? wmed : wmax;
    wb[idx] = f2bf(w[r]);
    return;
  }
  int n = b;
  __shared__ float fre[HWP];
  __shared__ int sc[32];
  if (t < HWP) {
    float s = 0.f;
    #pragma unroll
    for (int g = 0; g < 8; ++g) s += partial[(n * 8 + g) * HWP + t];
    fre[t] = s;
  }
  __syncthreads();
  if (t < HWP) {
    float v = fre[t];
    int rank = 0;
    for (int q = 0; q < HWP; ++q) {
      float u = fre[q];
      rank += ((u > v) || (u == v && q < t)) ? 1 : 0;
    }
    if (rank < 16) sc[rank] = t;                           // maxK: ranks 0..15
    else if (rank >= 89 && rank < 105) sc[rank - 73] = t;  // medK: ranks 89..104
  }
  __syncthreads();
  if (t < 32) {
    int p = sc[t];
    scene[n * 32 + t] = p;
    out[2 * NB * 4096 + n * 32 + t] = (float)(p / HH);            // rows
    out[2 * NB * 4096 + NB * 32 + n * 32 + t] = (float)(p % HH);  // cols
  }
}

// K3: coalesced gather (L3-resident x): stream 32-row chunks through LDS,
// extract 32 scene columns, write dense bf16 nodes[n][j<32][c<1024].
// 8 barriers/block (was 32), 8B/lane contiguous stores (was 2B).
__global__ __launch_bounds__(256) void k_gather(const float* __restrict__ x,
                                                const int* __restrict__ scene,
                                                ushort_t* __restrict__ nodes) {
  int n = blockIdx.x, cs = blockIdx.y, t = threadIdx.x;
  __shared__ alignas(16) float buf[32 * HWP];   // 25088 B
  __shared__ int s_sh[32];
  if (t < 32) s_sh[t] = scene[n * 32 + t];
  const int jj = t & 31;          // scene column
  const int r0 = (t >> 5) * 4;    // 8 row-groups x 4 rows
  for (int c0 = 0; c0 < 128; c0 += 32) {
    const float4* src = (const float4*)(x + ((size_t)n * CC + (size_t)cs * 128 + c0) * HWP);
    __syncthreads();                           // buf reuse + (iter0) s_sh
    #pragma unroll 2
    for (int i = t; i < (32 * HWP) / 4; i += 256) ((float4*)buf)[i] = src[i];
    __syncthreads();
    ushort_t* dst = nodes + ((size_t)n * 32 + jj) * CC + (size_t)cs * 128 + c0;
    int col = s_sh[jj];
    #pragma unroll
    for (int r = 0; r < 4; ++r) dst[r0 + r] = f2bf(buf[(r0 + r) * HWP + col]);
  }
}

// K4: bf16 MFMA GEMM + BN + ReLU + Lnorm apply. One block per (n,z), 4 waves.
__global__ __launch_bounds__(256) void k_main(
    const ushort_t* __restrict__ nodes, const ushort_t* __restrict__ wb,
    const float* __restrict__ g_max, const float* __restrict__ b_max,
    const float* __restrict__ m_max, const float* __restrict__ v_max,
    const float* __restrict__ g_med, const float* __restrict__ b_med,
    const float* __restrict__ m_med, const float* __restrict__ v_med,
    const int* __restrict__ scene, float* __restrict__ out) {
  constexpr int AP = 1032;               // padded row stride (ushorts)
  __shared__ ushort_t A_sh[16 * AP];
  __shared__ float Lsh[16][17];
  __shared__ float dinv[16];
  __shared__ int s_sh[16];
  __shared__ float y_sh[16][257];

  const int n = blockIdx.x;
  const int z = blockIdx.y;
  const int t = threadIdx.x;

  if (t < 16) s_sh[t] = scene[n * 32 + z * 16 + t];

  // stage A (16 x 1024 bf16) from nodes — fully coalesced 16B/lane
  {
    const ushort_t* src = nodes + ((size_t)n * 32 + (size_t)z * 16) * CC;
    #pragma unroll
    for (int i = t; i < 2048; i += 256) {
      int j = i >> 7, c8 = i & 127;
      *reinterpret_cast<short8*>(&A_sh[j * AP + c8 * 8]) =
          *reinterpret_cast<const short8*>(&src[j * CC + c8 * 8]);
    }
  }
  __syncthreads();   // s_sh + A_sh visible

  {
    const int i = t >> 4, j = t & 15;
    int pi = s_sh[i], pj = s_sh[j];
    float dr = (float)(pi / HH - pj / HH);
    float dc = (float)(pi % HH - pj % HH);
    Lsh[i][j] = 1.0f / (1.0f + sqrtf(dr * dr + dc * dc));
  }
  __syncthreads();
  if (t < 16) {
    float s = 0.f;
    #pragma unroll
    for (int j = 0; j < 16; ++j) s += Lsh[t][j];
    dinv[t] = rsqrtf(s);
  }

  const int w = t >> 6;
  const int l = t & 63;
  const int m = l & 15;
  const int quad = l >> 4;

  const ushort_t* Arow = &A_sh[m * AP + quad * 8];
  const ushort_t* B0 = wb + (size_t)z * (OO * CC) + (size_t)(w * 64 + m) * CC + quad * 8;

  float4v acc0 = {0.f, 0.f, 0.f, 0.f};
  float4v acc1 = acc0, acc2 = acc0, acc3 = acc0;

  __syncthreads();   // dinv visible

  #pragma unroll 4
  for (int k0 = 0; k0 < CC; k0 += 32) {
    short8 a  = *reinterpret_cast<const short8*>(Arow + k0);
    short8 b0 = *reinterpret_cast<const short8*>(B0 + k0);
    short8 b1 = *reinterpret_cast<const short8*>(B0 + 16 * CC + k0);
    short8 b2 = *reinterpret_cast<const short8*>(B0 + 32 * CC + k0);
    short8 b3 = *reinterpret_cast<const short8*>(B0 + 48 * CC + k0);
    acc0 = __builtin_amdgcn_mfma_f32_16x16x32_bf16(a, b0, acc0, 0, 0, 0);
    acc1 = __builtin_amdgcn_mfma_f32_16x16x32_bf16(a, b1, acc1, 0, 0, 0);
    acc2 = __builtin_amdgcn_mfma_f32_16x16x32_bf16(a, b2, acc2, 0, 0, 0);
    acc3 = __builtin_amdgcn_mfma_f32_16x16x32_bf16(a, b3, acc3, 0, 0, 0);
  }

  const float* gp = z ? g_med : g_max;
  const float* bp = z ? b_med : b_max;
  const float* mp = z ? m_med : m_max;
  const float* vp = z ? v_med : v_max;

  // BN + ReLU; scatter C-layout (col=lane&15, row=quad*4+reg) to LDS
  #pragma unroll
  for (int tt = 0; tt < 4; ++tt) {
    float4v av = (tt == 0) ? acc0 : (tt == 1) ? acc1 : (tt == 2) ? acc2 : acc3;
    int o = w * 64 + tt * 16 + m;
    float sc = gp[o] * rsqrtf(vp[o] + 1e-5f);
    float sh = bp[o] - mp[o] * sc;
    #pragma unroll
    for (int r = 0; r < 4; ++r) {
      int j = quad * 4 + r;
      float y = av[r] * sc + sh;
      y = fmaxf(y, 0.f);
      y_sh[j][o] = y * dinv[j];
    }
  }
  __syncthreads();

  // out[n,z,i,o] = dinv_i * sum_j L[i][j] * (dinv_j * y[j][o]); thread = o
  float yp[16];
  #pragma unroll
  for (int j = 0; j < 16; ++j) yp[j] = y_sh[j][t];
  float* ob = out + (size_t)z * (NB * 4096) + (size_t)n * 4096 + t;
  #pragma unroll
  for (int i = 0; i < 16; ++i) {
    float s = 0.f;
    #pragma unroll
    for (int j = 0; j < 16; ++j) s = fmaf(Lsh[i][j], yp[j], s);
    ob[(size_t)i * OO] = s * dinv[i];
  }
}

extern "C" void kernel_launch(void* const* d_in, const int* in_sizes, int n_in,
                              void* d_out, int out_size, void* d_ws, size_t ws_size,
                              hipStream_t stream) {
  const float* x     = (const float*)d_in[0];
  const float* w_max = (const float*)d_in[2];
  const float* g_max = (const float*)d_in[3];
  const float* b_max = (const float*)d_in[4];
  const float* m_max = (const float*)d_in[5];
  const float* v_max = (const float*)d_in[6];
  const float* w_med = (const float*)d_in[7];
  const float* g_med = (const float*)d_in[8];
  const float* b_med = (const float*)d_in[9];
  const float* m_med = (const float*)d_in[10];
  const float* v_med = (const float*)d_in[11];
  float* out = (float*)d_out;

  float* ws_f = (float*)d_ws;
  float* partial  = ws_f;                        // 200704 floats
  int* scene      = (int*)(ws_f + 200704);       // 4096 ints
  ushort_t* wb    = (ushort_t*)(ws_f + 204800);  // 524288 ushorts (1 MB)
  ushort_t* nodes = (ushort_t*)(ws_f + 466944);  // 128*32*1024 ushorts (8 MB)

  k_reduce<<<dim3(NB, 8), 256, 0, stream>>>(x, partial);
  k_misc<<<dim3(NB + 2048), 256, 0, stream>>>(partial, w_max, w_med, scene, out, wb);
  k_gather<<<dim3(NB, 8), 256, 0, stream>>>(x, scene, nodes);
  k_main<<<dim3(NB, 2), 256, 0, stream>>>(nodes, wb, g_max, b_max, m_max, v_max,
                                          g_med, b_med, m_med, v_med, scene, out);
}

// Round 5
// 211.429 us; speedup vs baseline: 1.0504x; 1.0342x over previous
//
#include <hip/hip_runtime.h>

#define NB 128
#define CC 1024
#define HWP 196
#define HH 14
#define OO 256

typedef unsigned short ushort_t;
typedef __attribute__((ext_vector_type(8))) short short8;
typedef __attribute__((ext_vector_type(4))) float float4v;

__device__ __forceinline__ ushort_t f2bf(float v) {
  union { float f; unsigned int u; } c; c.f = v;
  unsigned int u = c.u;
  unsigned int r = (u + 0x7FFFu + ((u >> 16) & 1u)) >> 16;   // RNE
  return (ushort_t)r;
}

// K1: fused (a) partial channel-sum — EXACT R1-R3 accumulation order
// (sequential over c within 128-group; groups summed sequentially in k_main).
// The medK rank selection is knife-edge sensitive to this FP order — do not
// re-vectorize across c. Blocks 0..1023: reduce. Blocks 1024..3071: bf16 cast.
__global__ __launch_bounds__(256) void k_prep(const float* __restrict__ x,
                                              const float* __restrict__ wmax,
                                              const float* __restrict__ wmed,
                                              float* __restrict__ partial,
                                              ushort_t* __restrict__ wb) {
  const int b = blockIdx.x, t = threadIdx.x;
  if (b >= 1024) {   // weight cast: 2048 blocks x 256 = 2*OO*CC elements
    int idx = (b - 1024) * 256 + t;
    int z = idx >> 18;
    int r = idx & (OO * CC - 1);
    const float* w = z ? wmed : wmax;
    wb[idx] = f2bf(w[r]);
    return;
  }
  const int n = b >> 3, cg = b & 7;
  const int p = t;
  if (p >= HWP) return;
  const float* base = x + ((size_t)n * CC + (size_t)cg * 128) * HWP + p;
  float s = 0.f;
  #pragma unroll 16
  for (int c = 0; c < 128; ++c) s += base[(size_t)c * HWP];
  partial[((size_t)n * 8 + cg) * HWP + p] = s;
}

// K2: per (n,z) block: in-block exact stable rank-select -> scene; scattered
// gather of A (16x1024) straight from L3-resident x; bf16 MFMA GEMM; BN+ReLU;
// Lnorm apply; writes graphs (+ rows/cols from z==0 blocks).
__global__ __launch_bounds__(256) void k_main(
    const float* __restrict__ x, const float* __restrict__ partial,
    const ushort_t* __restrict__ wb,
    const float* __restrict__ g_max, const float* __restrict__ b_max,
    const float* __restrict__ m_max, const float* __restrict__ v_max,
    const float* __restrict__ g_med, const float* __restrict__ b_med,
    const float* __restrict__ m_med, const float* __restrict__ v_med,
    float* __restrict__ out) {
  constexpr int AP = 1032;               // padded row stride (ushorts)
  __shared__ ushort_t A_sh[16 * AP];     // 33 KB
  __shared__ float fre[HWP];
  __shared__ int sc[32];
  __shared__ float Lsh[16][17];
  __shared__ float dinv[16];
  __shared__ float y_sh[16][257];        // 16.4 KB

  const int n = blockIdx.x;
  const int z = blockIdx.y;
  const int t = threadIdx.x;

  // ---- select: fre = sum of 8 partials (sequential); stable ranks ----
  if (t < HWP) {
    float s = 0.f;
    #pragma unroll
    for (int g = 0; g < 8; ++g) s += partial[((size_t)n * 8 + g) * HWP + t];
    fre[t] = s;
  }
  __syncthreads();
  if (t < HWP) {
    float v = fre[t];
    int rank = 0;
    #pragma unroll 4
    for (int q = 0; q < HWP; ++q) {
      float u = fre[q];
      rank += ((u > v) || (u == v && q < t)) ? 1 : 0;
    }
    if (rank < 16) sc[rank] = t;                           // maxK: ranks 0..15
    else if (rank >= 89 && rank < 105) sc[rank - 73] = t;  // medK: ranks 89..104
  }
  __syncthreads();

  if (z == 0 && t < 32) {
    int p = sc[t];
    out[2 * NB * 4096 + n * 32 + t] = (float)(p / HH);            // rows
    out[2 * NB * 4096 + NB * 32 + n * 32 + t] = (float)(p % HH);  // cols
  }

  // ---- gather A (16 x 1024 bf16) from x (L3-resident after k_prep) ----
  {
    const int j = t & 15;
    const int kg = t >> 4;             // 16 k-groups of 64 channels
    const int sj = sc[z * 16 + j];
    const float* xb = x + (size_t)n * (CC * HWP) + sj;
    ushort_t* arow = &A_sh[j * AP];
    #pragma unroll 8
    for (int u = 0; u < 64; ++u) {
      int k = kg * 64 + u;
      arow[k] = f2bf(xb[(size_t)k * HWP]);
    }
  }
  // ---- L matrix ----
  {
    const int i = t >> 4, j = t & 15;
    int pi = sc[z * 16 + i], pj = sc[z * 16 + j];
    float dr = (float)(pi / HH - pj / HH);
    float dc = (float)(pi % HH - pj % HH);
    Lsh[i][j] = 1.0f / (1.0f + sqrtf(dr * dr + dc * dc));
  }
  __syncthreads();
  if (t < 16) {
    float s = 0.f;
    #pragma unroll
    for (int j = 0; j < 16; ++j) s += Lsh[t][j];
    dinv[t] = rsqrtf(s);
  }

  const int w = t >> 6;
  const int l = t & 63;
  const int m = l & 15;
  const int quad = l >> 4;

  const ushort_t* Arow = &A_sh[m * AP + quad * 8];
  const ushort_t* B0 = wb + (size_t)z * (OO * CC) + (size_t)(w * 64 + m) * CC + quad * 8;

  float4v acc0 = {0.f, 0.f, 0.f, 0.f};
  float4v acc1 = acc0, acc2 = acc0, acc3 = acc0;

  __syncthreads();   // dinv + A_sh visible

  #pragma unroll 4
  for (int k0 = 0; k0 < CC; k0 += 32) {
    short8 a  = *reinterpret_cast<const short8*>(Arow + k0);
    short8 b0 = *reinterpret_cast<const short8*>(B0 + k0);
    short8 b1 = *reinterpret_cast<const short8*>(B0 + 16 * CC + k0);
    short8 b2 = *reinterpret_cast<const short8*>(B0 + 32 * CC + k0);
    short8 b3 = *reinterpret_cast<const short8*>(B0 + 48 * CC + k0);
    acc0 = __builtin_amdgcn_mfma_f32_16x16x32_bf16(a, b0, acc0, 0, 0, 0);
    acc1 = __builtin_amdgcn_mfma_f32_16x16x32_bf16(a, b1, acc1, 0, 0, 0);
    acc2 = __builtin_amdgcn_mfma_f32_16x16x32_bf16(a, b2, acc2, 0, 0, 0);
    acc3 = __builtin_amdgcn_mfma_f32_16x16x32_bf16(a, b3, acc3, 0, 0, 0);
  }

  const float* gp = z ? g_med : g_max;
  const float* bp = z ? b_med : b_max;
  const float* mp = z ? m_med : m_max;
  const float* vp = z ? v_med : v_max;

  // BN + ReLU; scatter C-layout (col=lane&15, row=quad*4+reg) to LDS
  #pragma unroll
  for (int tt = 0; tt < 4; ++tt) {
    float4v av = (tt == 0) ? acc0 : (tt == 1) ? acc1 : (tt == 2) ? acc2 : acc3;
    int o = w * 64 + tt * 16 + m;
    float scale = gp[o] * rsqrtf(vp[o] + 1e-5f);
    float shift = bp[o] - mp[o] * scale;
    #pragma unroll
    for (int r = 0; r < 4; ++r) {
      int j = quad * 4 + r;
      float y = av[r] * scale + shift;
      y = fmaxf(y, 0.f);
      y_sh[j][o] = y * dinv[j];
    }
  }
  __syncthreads();

  // out[n,z,i,o] = dinv_i * sum_j L[i][j] * (dinv_j * y[j][o]); thread = o
  float yp[16];
  #pragma unroll
  for (int j = 0; j < 16; ++j) yp[j] = y_sh[j][t];
  float* ob = out + (size_t)z * (NB * 4096) + (size_t)n * 4096 + t;
  #pragma unroll
  for (int i = 0; i < 16; ++i) {
    float s = 0.f;
    #pragma unroll
    for (int j = 0; j < 16; ++j) s = fmaf(Lsh[i][j], yp[j], s);
    ob[(size_t)i * OO] = s * dinv[i];
  }
}

extern "C" void kernel_launch(void* const* d_in, const int* in_sizes, int n_in,
                              void* d_out, int out_size, void* d_ws, size_t ws_size,
                              hipStream_t stream) {
  const float* x     = (const float*)d_in[0];
  const float* w_max = (const float*)d_in[2];
  const float* g_max = (const float*)d_in[3];
  const float* b_max = (const float*)d_in[4];
  const float* m_max = (const float*)d_in[5];
  const float* v_max = (const float*)d_in[6];
  const float* w_med = (const float*)d_in[7];
  const float* g_med = (const float*)d_in[8];
  const float* b_med = (const float*)d_in[9];
  const float* m_med = (const float*)d_in[10];
  const float* v_med = (const float*)d_in[11];
  float* out = (float*)d_out;

  float* ws_f = (float*)d_ws;
  float* partial  = ws_f;                        // 128*8*196 = 200704 floats
  ushort_t* wb    = (ushort_t*)(ws_f + 200704);  // 2*256*1024 ushorts (1 MB)

  k_prep<<<dim3(1024 + 2048), 256, 0, stream>>>(x, w_max, w_med, partial, wb);
  k_main<<<dim3(NB, 2), 256, 0, stream>>>(x, partial, wb,
                                          g_max, b_max, m_max, v_max,
                                          g_med, b_med, m_med, v_med, out);
}

// Round 6
// 208.275 us; speedup vs baseline: 1.0663x; 1.0151x over previous
//
#include <hip/hip_runtime.h>

#define NB 128
#define CC 1024
#define HWP 196
#define HH 14
#define OO 256

typedef unsigned short ushort_t;
typedef __attribute__((ext_vector_type(8))) short short8;
typedef __attribute__((ext_vector_type(4))) float float4v;

__device__ __forceinline__ ushort_t f2bf(float v) {
  union { float f; unsigned int u; } c; c.f = v;
  unsigned int u = c.u;
  unsigned int r = (u + 0x7FFFu + ((u >> 16) & 1u)) >> 16;   // RNE
  return (ushort_t)r;
}

// K1: fused (a) partial channel-sum, (b) weight bf16 cast.
// Reduce: one wave per (n,cg); lanes 0..48 hold float4 (4 consecutive p).
// Component-wise accumulation over c=0..127 ascending — bit-identical per-p
// FP order to the scalar R5 version (medK rank selection is knife-edge
// sensitive to this order; do NOT reorder the c loop).
// Blocks 0..255: reduce (4 (n,cg) units per block, one per wave).
// Blocks 256..2303: bf16 weight cast.
__global__ __launch_bounds__(256) void k_prep(const float* __restrict__ x,
                                              const float* __restrict__ wmax,
                                              const float* __restrict__ wmed,
                                              float* __restrict__ partial,
                                              ushort_t* __restrict__ wb) {
  const int b = blockIdx.x, t = threadIdx.x;
  if (b >= 256) {   // weight cast: 2048 blocks x 256 = 2*OO*CC elements
    int idx = (b - 256) * 256 + t;
    int z = idx >> 18;
    int r = idx & (OO * CC - 1);
    const float* w = z ? wmed : wmax;
    wb[idx] = f2bf(w[r]);
    return;
  }
  const int unit = b * 4 + (t >> 6);     // (n,cg) unit, one per wave
  const int lane = t & 63;
  if (lane >= 49) return;                // 49 float4s cover 196 floats
  const int n = unit >> 3, cg = unit & 7;
  const float4* base = (const float4*)(x + ((size_t)n * CC + (size_t)cg * 128) * HWP);
  float4 s = {0.f, 0.f, 0.f, 0.f};
  #pragma unroll 16
  for (int c = 0; c < 128; ++c) {
    float4 v = base[c * 49 + lane];
    s.x += v.x; s.y += v.y; s.z += v.z; s.w += v.w;   // per-p sequential order
  }
  ((float4*)(partial + ((size_t)n * 8 + cg) * HWP))[lane] = s;
}

// K2: per (n,z) block, 512 threads (8 waves): in-block exact stable rank-select;
// scattered gather of A (16x1024) from L3-resident x (8 waves x 16-unroll ->
// ~32KB/CU outstanding, 4x R5); bf16 MFMA GEMM (8 waves x 32 cols); BN+ReLU;
// Lnorm apply; writes graphs (+ rows/cols from z==0 blocks).
__global__ __launch_bounds__(512, 2) void k_main(
    const float* __restrict__ x, const float* __restrict__ partial,
    const ushort_t* __restrict__ wb,
    const float* __restrict__ g_max, const float* __restrict__ b_max,
    const float* __restrict__ m_max, const float* __restrict__ v_max,
    const float* __restrict__ g_med, const float* __restrict__ b_med,
    const float* __restrict__ m_med, const float* __restrict__ v_med,
    float* __restrict__ out) {
  constexpr int AP = 1032;               // padded row stride (ushorts)
  __shared__ alignas(16) ushort_t A_sh[16 * AP];   // 33 KB
  __shared__ float fre[HWP];
  __shared__ int sc[32];
  __shared__ float Lsh[16][17];
  __shared__ float dinv[16];
  __shared__ float y_sh[16][257];        // 16.4 KB

  const int n = blockIdx.x;
  const int z = blockIdx.y;
  const int t = threadIdx.x;

  // ---- select: fre = sum of 8 partials (sequential); stable ranks ----
  if (t < HWP) {
    float s = 0.f;
    #pragma unroll
    for (int g = 0; g < 8; ++g) s += partial[((size_t)n * 8 + g) * HWP + t];
    fre[t] = s;
  }
  __syncthreads();
  if (t < HWP) {
    float v = fre[t];
    int rank = 0;
    #pragma unroll 4
    for (int q = 0; q < HWP; ++q) {
      float u = fre[q];
      rank += ((u > v) || (u == v && q < t)) ? 1 : 0;
    }
    if (rank < 16) sc[rank] = t;                           // maxK: ranks 0..15
    else if (rank >= 89 && rank < 105) sc[rank - 73] = t;  // medK: ranks 89..104
  }
  __syncthreads();

  if (z == 0 && t < 32) {
    int p = sc[t];
    out[2 * NB * 4096 + n * 32 + t] = (float)(p / HH);            // rows
    out[2 * NB * 4096 + NB * 32 + n * 32 + t] = (float)(p % HH);  // cols
  }

  // ---- gather A (16 x 1024 bf16) from x; 512 threads, 32 loads each ----
  {
    const int j = t & 15;
    const int g = t >> 4;              // 32 channel-groups of 32
    const int sj = sc[z * 16 + j];
    const float* xb = x + (size_t)n * (CC * HWP) + (size_t)g * 32 * HWP + sj;
    ushort_t* arow = &A_sh[j * AP + g * 32];
    #pragma unroll 16
    for (int u = 0; u < 32; ++u) {
      arow[u] = f2bf(xb[(size_t)u * HWP]);
    }
  }
  // ---- L matrix ----
  if (t < 256) {
    const int i = t >> 4, j = t & 15;
    int pi = sc[z * 16 + i], pj = sc[z * 16 + j];
    float dr = (float)(pi / HH - pj / HH);
    float dc = (float)(pi % HH - pj % HH);
    Lsh[i][j] = 1.0f / (1.0f + sqrtf(dr * dr + dc * dc));
  }
  __syncthreads();
  if (t < 16) {
    float s = 0.f;
    #pragma unroll
    for (int j = 0; j < 16; ++j) s += Lsh[t][j];
    dinv[t] = rsqrtf(s);
  }

  const int w = t >> 6;                  // 8 waves, 32 output cols each
  const int l = t & 63;
  const int m = l & 15;
  const int quad = l >> 4;

  const ushort_t* Arow = &A_sh[m * AP + quad * 8];
  const ushort_t* B0 = wb + (size_t)z * (OO * CC) + (size_t)(w * 32 + m) * CC + quad * 8;

  float4v acc0 = {0.f, 0.f, 0.f, 0.f};
  float4v acc1 = acc0;

  __syncthreads();   // dinv + A_sh visible

  #pragma unroll 4
  for (int k0 = 0; k0 < CC; k0 += 32) {
    short8 a  = *reinterpret_cast<const short8*>(Arow + k0);
    short8 b0 = *reinterpret_cast<const short8*>(B0 + k0);
    short8 b1 = *reinterpret_cast<const short8*>(B0 + 16 * CC + k0);
    acc0 = __builtin_amdgcn_mfma_f32_16x16x32_bf16(a, b0, acc0, 0, 0, 0);
    acc1 = __builtin_amdgcn_mfma_f32_16x16x32_bf16(a, b1, acc1, 0, 0, 0);
  }

  const float* gp = z ? g_med : g_max;
  const float* bp = z ? b_med : b_max;
  const float* mp = z ? m_med : m_max;
  const float* vp = z ? v_med : v_max;

  // BN + ReLU; scatter C-layout (col=lane&15, row=quad*4+reg) to LDS
  #pragma unroll
  for (int tt = 0; tt < 2; ++tt) {
    float4v av = tt ? acc1 : acc0;
    int o = w * 32 + tt * 16 + m;
    float scale = gp[o] * rsqrtf(vp[o] + 1e-5f);
    float shift = bp[o] - mp[o] * scale;
    #pragma unroll
    for (int r = 0; r < 4; ++r) {
      int j = quad * 4 + r;
      float y = av[r] * scale + shift;
      y = fmaxf(y, 0.f);
      y_sh[j][o] = y * dinv[j];
    }
  }
  __syncthreads();

  // out[n,z,i,o] = dinv_i * sum_j L[i][j] * (dinv_j * y[j][o])
  // 512 threads: o = t&255, half-i-range per t>>8
  {
    const int o = t & 255;
    const int ih = (t >> 8) * 8;
    float yp[16];
    #pragma unroll
    for (int j = 0; j < 16; ++j) yp[j] = y_sh[j][o];
    float* ob = out + (size_t)z * (NB * 4096) + (size_t)n * 4096 + o;
    #pragma unroll
    for (int i2 = 0; i2 < 8; ++i2) {
      const int i = ih + i2;
      float s = 0.f;
      #pragma unroll
      for (int j = 0; j < 16; ++j) s = fmaf(Lsh[i][j], yp[j], s);
      ob[(size_t)i * OO] = s * dinv[i];
    }
  }
}

extern "C" void kernel_launch(void* const* d_in, const int* in_sizes, int n_in,
                              void* d_out, int out_size, void* d_ws, size_t ws_size,
                              hipStream_t stream) {
  const float* x     = (const float*)d_in[0];
  const float* w_max = (const float*)d_in[2];
  const float* g_max = (const float*)d_in[3];
  const float* b_max = (const float*)d_in[4];
  const float* m_max = (const float*)d_in[5];
  const float* v_max = (const float*)d_in[6];
  const float* w_med = (const float*)d_in[7];
  const float* g_med = (const float*)d_in[8];
  const float* b_med = (const float*)d_in[9];
  const float* m_med = (const float*)d_in[10];
  const float* v_med = (const float*)d_in[11];
  float* out = (float*)d_out;

  float* ws_f = (float*)d_ws;
  float* partial  = ws_f;                        // 128*8*196 = 200704 floats
  ushort_t* wb    = (ushort_t*)(ws_f + 200704);  // 2*256*1024 ushorts (1 MB)

  k_prep<<<dim3(256 + 2048), 256, 0, stream>>>(x, w_max, w_med, partial, wb);
  k_main<<<dim3(NB, 2), 512, 0, stream>>>(x, partial, wb,
                                          g_max, b_max, m_max, v_max,
                                          g_med, b_med, m_med, v_med, out);
}